// Round 14
// baseline (402.000 us; speedup 1.0000x reference)
//
#include <hip/hip_runtime.h>
#include <hip/hip_bf16.h>

#define N_NODES 64000
#define BN_EPS 1e-5f
#define NBL 512      // radix blocks per type
#define NBKT 250     // coarse buckets = N_NODES / 256
#define NCHK 32      // Hist chunks (NBL/16)

typedef __attribute__((ext_vector_type(8))) short short8v;   // 8 bf16 (4 VGPRs)
typedef __attribute__((ext_vector_type(4))) float f32x4;

static inline int cdiv(long long a, int b) { return (int)((a + b - 1) / b); }

__device__ inline float bf2f(unsigned int u) {
  union { unsigned int i; float f; } v; v.i = u << 16; return v.f;
}
__device__ inline unsigned short f2bf(float f) {
  __hip_bfloat16 h = __float2bfloat16(f);
  return *reinterpret_cast<unsigned short*>(&h);
}

// ================= prep work items (merged into r1p) =================
__device__ inline void pack_one(const float* __restrict__ W, unsigned short* __restrict__ Bp,
                                int idx, int NOUT, int k_off, int NB) {
  int kl = idx / NOUT, n = idx - kl * NOUT;
  int k = k_off + kl;
  int kb = k >> 5, nb = n >> 4;
  int lane = (((k >> 3) & 3) << 4) | (n & 15);
  int e = k & 7;
  Bp[(((kb * NB) + nb) * 64 + lane) * 8 + e] = f2bf(W[idx]);
}

#define XB_N (N_NODES * 16)
#define PREP_ITEMS (XB_N + 18432 + 36864 + 9216 + 16384 + 96 + 128 + 192 + 256)
#define R1_BLOCKS (3 * NBL)

// ===== r1p: histograms of src>>8 and dst>>8 (blocks < R1_BLOCKS), prep (rest) =====
__global__ void r1p_kernel(const int* __restrict__ s0, const int* __restrict__ s1,
                           const int* __restrict__ s2, const int* __restrict__ d0,
                           const int* __restrict__ d1, const int* __restrict__ d2,
                           int E0, int E1, int E2,
                           int* __restrict__ HistS, int* __restrict__ HistD,
                           const float* __restrict__ x, unsigned short* __restrict__ xb,
                           const float* w00, const float* w01, const float* w02,
                           const float* w10, const float* w11, const float* w12,
                           const float* fc0w, const float* fc1w,
                           const float* b00, const float* b01, const float* b02,
                           const float* b10, const float* b11, const float* b12,
                           unsigned short* B0p, unsigned short* B1p,
                           unsigned short* fc0p, unsigned short* fc1p,
                           float* b0s, float* b1s, float* statsA, float* statsB) {
  if (blockIdx.x < R1_BLOCKS) {
    int t = blockIdx.x / NBL, blk = blockIdx.x - t * NBL;
    const int* src = t == 0 ? s0 : (t == 1 ? s1 : s2);
    const int* dst = t == 0 ? d0 : (t == 1 ? d1 : d2);
    int E = t == 0 ? E0 : (t == 1 ? E1 : E2);
    __shared__ int hs[256], hd[256];
    hs[threadIdx.x] = 0; hd[threadIdx.x] = 0;
    __syncthreads();
    int ch = (E + NBL - 1) / NBL;
    int lo = blk * ch, hi = min(lo + ch, E);
    for (int i = lo + threadIdx.x; i < hi; i += 256) {
      atomicAdd(&hs[src[i] >> 8], 1);
      atomicAdd(&hd[dst[i] >> 8], 1);
    }
    __syncthreads();
    HistS[(t * NBL + blk) * 256 + threadIdx.x] = hs[threadIdx.x];
    HistD[(t * NBL + blk) * 256 + threadIdx.x] = hd[threadIdx.x];
    return;
  }
  int idx = (blockIdx.x - R1_BLOCKS) * blockDim.x + threadIdx.x;
  if (idx < XB_N) {
    float4 v = ((const float4*)x)[idx];
    ushort4 o;
    o.x = f2bf(v.x); o.y = f2bf(v.y); o.z = f2bf(v.z); o.w = f2bf(v.w);
    ((ushort4*)xb)[idx] = o;
    return;
  }
  idx -= XB_N;
  if (idx < 3 * 6144) {
    int e = idx / 6144;
    pack_one(e == 0 ? w00 : (e == 1 ? w01 : w02), B0p, idx - e * 6144, 96, e * 64, 6);
    return;
  }
  idx -= 18432;
  if (idx < 3 * 12288) {
    int e = idx / 12288;
    pack_one(e == 0 ? w10 : (e == 1 ? w11 : w12), B1p, idx - e * 12288, 128, e * 96, 8);
    return;
  }
  idx -= 36864;
  if (idx < 9216) { pack_one(fc0w, fc0p, idx, 96, 0, 6); return; }
  idx -= 9216;
  if (idx < 16384) { pack_one(fc1w, fc1p, idx, 128, 0, 8); return; }
  idx -= 16384;
  if (idx < 96) { b0s[idx] = b00[idx] + b01[idx] + b02[idx]; return; }
  idx -= 96;
  if (idx < 128) { b1s[idx] = b10[idx] + b11[idx] + b12[idx]; return; }
  idx -= 128;
  if (idx < 192) { statsA[idx] = 0.f; return; }
  idx -= 192;
  if (idx < 256) { statsB[idx] = 0.f; return; }
}

// ===== r2a: per-(side,type,chunk) partial bin sums over 16 Hist blocks =====
__global__ void r2a_kernel(const int* __restrict__ HistS, const int* __restrict__ HistD,
                           int* __restrict__ partial) {
  int b = blockIdx.x;               // 192 = 2 sides x 3 types x 32 chunks
  int side = b / 96, rem = b - side * 96;
  int t = rem / NCHK, chunk = rem - t * NCHK;
  const int* H = (side ? HistD : HistS) + (size_t)t * NBL * 256;
  int s = 0;
  for (int j = 0; j < 16; ++j) s += H[(chunk * 16 + j) * 256 + threadIdx.x];
  partial[((side * 3 + t) * NCHK + chunk) * 256 + threadIdx.x] = s;
}

// ===== r2b: per-(side,type) bin scan -> bbase; rewrite partial to chunk bases =====
__global__ void r2b_kernel(int* __restrict__ partial, int* __restrict__ bbaseS,
                           int* __restrict__ bbaseD) {
  int side = blockIdx.x / 3, t = blockIdx.x - side * 3;
  int bin = threadIdx.x;
  int* part = partial + (size_t)(side * 3 + t) * NCHK * 256;
  int* bb = (side ? bbaseD : bbaseS) + t * (NBKT + 1);
  int tot = 0;
  for (int c = 0; c < NCHK; ++c) tot += part[c * 256 + bin];
  __shared__ int s[256];
  s[bin] = tot;
  __syncthreads();
  for (int o = 1; o < 256; o <<= 1) {
    int a = (bin >= o) ? s[bin - o] : 0;
    __syncthreads();
    s[bin] += a;
    __syncthreads();
  }
  int base = s[bin] - tot;
  if (bin <= NBKT) bb[bin] = base;
  int run = base;
  for (int c = 0; c < NCHK; ++c) {
    int v = part[c * 256 + bin];
    part[c * 256 + bin] = run;
    run += v;
  }
}

// ===== r2c: rewrite each chunk's 16 Hist blocks with running offsets =====
__global__ void r2c_kernel(int* __restrict__ HistS, int* __restrict__ HistD,
                           const int* __restrict__ partial) {
  int b = blockIdx.x;
  int side = b / 96, rem = b - side * 96;
  int t = rem / NCHK, chunk = rem - t * NCHK;
  int* H = (side ? HistD : HistS) + (size_t)t * NBL * 256;
  int run = partial[((side * 3 + t) * NCHK + chunk) * 256 + threadIdx.x];
  for (int j = 0; j < 16; ++j) {
    int blk = chunk * 16 + j;
    int v = H[blk * 256 + threadIdx.x];
    H[blk * 256 + threadIdx.x] = run;
    run += v;
  }
}

// ===== r3ab: one pass scatters both sides =====
__global__ void r3ab_kernel(const int* __restrict__ s0, const int* __restrict__ s1,
                            const int* __restrict__ s2, const int* __restrict__ d0,
                            const int* __restrict__ d1, const int* __restrict__ d2,
                            int E0, int E1, int E2, const int* __restrict__ HistS,
                            const int* __restrict__ HistD, unsigned int* __restrict__ tmp,
                            unsigned char* __restrict__ tmp8) {
  int t = blockIdx.x / NBL, blk = blockIdx.x - t * NBL;
  const int* src = t == 0 ? s0 : (t == 1 ? s1 : s2);
  const int* dst = t == 0 ? d0 : (t == 1 ? d1 : d2);
  int E = t == 0 ? E0 : (t == 1 ? E1 : E2);
  int teo = (t == 0 ? 0 : (t == 1 ? E0 : E0 + E1));
  unsigned int* tp = tmp + teo;
  unsigned char* t8 = tmp8 + teo;
  __shared__ int offS[256], offD[256];
  offS[threadIdx.x] = HistS[(t * NBL + blk) * 256 + threadIdx.x];
  offD[threadIdx.x] = HistD[(t * NBL + blk) * 256 + threadIdx.x];
  __syncthreads();
  int ch = (E + NBL - 1) / NBL;
  int lo = blk * ch, hi = min(lo + ch, E);
  for (int i = lo + threadIdx.x; i < hi; i += 256) {
    int s = src[i], d = dst[i];
    int q = atomicAdd(&offS[s >> 8], 1);
    t8[q] = (unsigned char)(s & 255);
    int p = atomicAdd(&offD[d >> 8], 1);
    tp[p] = ((unsigned)(d & 255) << 16) | (unsigned)s;
  }
}

__global__ void r4b_kernel(const unsigned char* __restrict__ tmp8,
                           const int* __restrict__ bbaseS, int E0, int E1, int E2,
                           float* __restrict__ rs_out) {
  int t = blockIdx.x / NBKT, b = blockIdx.x - t * NBKT;
  const int* bb = bbaseS + t * (NBKT + 1);
  const unsigned char* tp = tmp8 + (t == 0 ? 0 : (t == 1 ? E0 : E0 + E1));
  int lo = bb[b], hi = bb[b + 1];
  __shared__ int c[256];
  c[threadIdx.x] = 0;
  __syncthreads();
  for (int i = lo + threadIdx.x; i < hi; i += 256) atomicAdd(&c[tp[i]], 1);
  __syncthreads();
  rs_out[t * N_NODES + b * 256 + threadIdx.x] = rsqrtf(fmaxf((float)c[threadIdx.x], 1.0f));
}

__global__ void r4_kernel(const unsigned int* __restrict__ tmp,
                          const int* __restrict__ bbaseD, int E0, int E1, int E2,
                          const float* __restrict__ rs_out_base,
                          unsigned int* __restrict__ es, int* __restrict__ row_ptr,
                          float* __restrict__ rs_in) {
  int t = blockIdx.x / NBKT, b = blockIdx.x - t * NBKT;
  const int* bb = bbaseD + t * (NBKT + 1);
  int teo = (t == 0 ? 0 : (t == 1 ? E0 : E0 + E1));
  int E = t == 0 ? E0 : (t == 1 ? E1 : E2);
  const unsigned int* tp = tmp + teo;
  unsigned int* esp = es + teo;
  const float* ro = rs_out_base + t * N_NODES;
  int lo = bb[b], hi = bb[b + 1];
  __shared__ int c[256], s[256];
  c[threadIdx.x] = 0;
  __syncthreads();
  for (int i = lo + threadIdx.x; i < hi; i += 256) atomicAdd(&c[tp[i] >> 16], 1);
  __syncthreads();
  int v = c[threadIdx.x];
  s[threadIdx.x] = v;
  __syncthreads();
  for (int o = 1; o < 256; o <<= 1) {
    int a = (threadIdx.x >= o) ? s[threadIdx.x - o] : 0;
    __syncthreads();
    s[threadIdx.x] += a;
    __syncthreads();
  }
  int excl = s[threadIdx.x] - v;
  int node = b * 256 + threadIdx.x;
  rs_in[t * N_NODES + node] = rsqrtf(fmaxf((float)v, 1.0f));
  row_ptr[t * (N_NODES + 1) + node] = lo + excl;
  if (b == NBKT - 1 && threadIdx.x == 255) row_ptr[t * (N_NODES + 1) + N_NODES] = E;
  __syncthreads();
  s[threadIdx.x] = lo + excl;
  __syncthreads();
  for (int i = lo + threadIdx.x; i < hi; i += 256) {
    unsigned int w = tp[i];
    int p = atomicAdd(&s[w >> 16], 1);
    unsigned int sid = w & 0xFFFF;
    unsigned int rb = (unsigned int)f2bf(ro[sid]);
    esp[p] = (rb << 16) | sid;
  }
}

// ---- merged pull aggregation: 2 half-wave slots x ILP4 = 8 edges in flight ----
template<int D, int STR>
__global__ __launch_bounds__(256) void gather3_kernel(
    const unsigned int* __restrict__ hb32, const int* __restrict__ row_ptr_base,
    const unsigned int* __restrict__ es_base, const float* __restrict__ rs_in_base,
    unsigned int* __restrict__ out32, int E0, int E01) {
  constexpr int RW = D / 2;    // row width in uints
  constexpr int SW = STR / 2;  // output row stride in uints
  int gwid = (blockIdx.x * blockDim.x + threadIdx.x) >> 6;
  int lane = threadIdx.x & 63;
  if (gwid >= 3 * N_NODES) return;
  int t = (gwid >= N_NODES) + (gwid >= 2 * N_NODES);
  int node = gwid - t * N_NODES;
  int eoff = t == 0 ? 0 : (t == 1 ? E0 : E01);
  const int* row_ptr = row_ptr_base + t * (N_NODES + 1);
  const unsigned int* es = es_base + eoff;
  const float* rs_in = rs_in_base + t * N_NODES;

  int slot = lane >> 5, c = lane & 31;
  const bool xtra = (D == 96) && (c < 16);
  int lo = row_ptr[node], hi = row_ptr[node + 1];

  float aL0 = 0.f, aL1 = 0.f, aL2 = 0.f, aL3 = 0.f;
  float aH0 = 0.f, aH1 = 0.f, aH2 = 0.f, aH3 = 0.f;
  float bL0 = 0.f, bL1 = 0.f, bL2 = 0.f, bL3 = 0.f;
  float bH0 = 0.f, bH1 = 0.f, bH2 = 0.f, bH3 = 0.f;

  int e = lo + slot;
  for (; e + 6 < hi; e += 8) {
    unsigned int w0 = es[e], w1 = es[e + 2], w2 = es[e + 4], w3 = es[e + 6];
    int s0 = w0 & 0xFFFF, s1 = w1 & 0xFFFF, s2 = w2 & 0xFFFF, s3 = w3 & 0xFFFF;
    float r0 = bf2f(w0 >> 16), r1 = bf2f(w1 >> 16), r2 = bf2f(w2 >> 16), r3 = bf2f(w3 >> 16);
    unsigned int u0 = hb32[s0 * RW + c], u1 = hb32[s1 * RW + c];
    unsigned int u2 = hb32[s2 * RW + c], u3 = hb32[s3 * RW + c];
    aL0 += r0 * bf2f(u0 & 0xFFFF); aH0 += r0 * bf2f(u0 >> 16);
    aL1 += r1 * bf2f(u1 & 0xFFFF); aH1 += r1 * bf2f(u1 >> 16);
    aL2 += r2 * bf2f(u2 & 0xFFFF); aH2 += r2 * bf2f(u2 >> 16);
    aL3 += r3 * bf2f(u3 & 0xFFFF); aH3 += r3 * bf2f(u3 >> 16);
    if (D == 96) {
      if (xtra) {
        unsigned int v0 = hb32[s0 * RW + 32 + c], v1 = hb32[s1 * RW + 32 + c];
        unsigned int v2 = hb32[s2 * RW + 32 + c], v3 = hb32[s3 * RW + 32 + c];
        bL0 += r0 * bf2f(v0 & 0xFFFF); bH0 += r0 * bf2f(v0 >> 16);
        bL1 += r1 * bf2f(v1 & 0xFFFF); bH1 += r1 * bf2f(v1 >> 16);
        bL2 += r2 * bf2f(v2 & 0xFFFF); bH2 += r2 * bf2f(v2 >> 16);
        bL3 += r3 * bf2f(v3 & 0xFFFF); bH3 += r3 * bf2f(v3 >> 16);
      }
    }
  }
  for (; e < hi; e += 2) {
    unsigned int w = es[e];
    int s = w & 0xFFFF;
    float r = bf2f(w >> 16);
    unsigned int u = hb32[s * RW + c];
    aL0 += r * bf2f(u & 0xFFFF); aH0 += r * bf2f(u >> 16);
    if (D == 96) {
      if (xtra) {
        unsigned int v = hb32[s * RW + 32 + c];
        bL0 += r * bf2f(v & 0xFFFF); bH0 += r * bf2f(v >> 16);
      }
    }
  }

  float aL = (aL0 + aL1) + (aL2 + aL3);
  float aH = (aH0 + aH1) + (aH2 + aH3);
  aL += __shfl_xor(aL, 32);
  aH += __shfl_xor(aH, 32);
  float bL = 0.f, bH = 0.f;
  if (D == 96) {
    bL = (bL0 + bL1) + (bL2 + bL3);
    bH = (bH0 + bH1) + (bH2 + bH3);
    bL += __shfl_xor(bL, 32);
    bH += __shfl_xor(bH, 32);
  }
  if (slot == 0) {
    float ri = rs_in[node];
    unsigned int o = ((unsigned int)f2bf(aH * ri) << 16) | (unsigned int)f2bf(aL * ri);
    __builtin_nontemporal_store(o, &out32[(size_t)node * SW + t * RW + c]);
    if (D == 96) {
      if (xtra) {
        unsigned int o2 = ((unsigned int)f2bf(bH * ri) << 16) | (unsigned int)f2bf(bL * ri);
        __builtin_nontemporal_store(o2, &out32[(size_t)node * SW + t * RW + 32 + c]);
      }
    }
  }
}

// ---- MFMA GEMM, col-split x2 (2 waves share a 16-row tile via L1), bf16 out, stats ----
template<int K, int NOUT>
__global__ void gemm_kernel(const unsigned short* __restrict__ A,
                            const unsigned short* __restrict__ Bp,
                            const float* __restrict__ bias,
                            unsigned short* __restrict__ outp,
                            float* __restrict__ stats) {
  constexpr int NBf = NOUT / 16;
  constexpr int NBh = NOUT / 32;
  constexpr int KB = K / 32;
  __shared__ float ls[NOUT], lq[NOUT];
  for (int i = threadIdx.x; i < NOUT; i += blockDim.x) { ls[i] = 0.f; lq[i] = 0.f; }
  __syncthreads();
  int gw = (blockIdx.x * blockDim.x + threadIdx.x) >> 6;
  int lane = threadIdx.x & 63;
  int rt = gw >> 1, chh = gw & 1;   // consecutive waves share the row tile (L1 reuse)
  int row0 = rt * 16;
  int arow = row0 + (lane & 15);
  int kgrp = lane >> 4;
  f32x4 acc[NBh];
#pragma unroll
  for (int i = 0; i < NBh; ++i) acc[i] = (f32x4){0.f, 0.f, 0.f, 0.f};
  const short8v* ap = (const short8v*)(A + (long long)arow * K + kgrp * 8);
  const short8v* bp = (const short8v*)Bp;
#pragma unroll
  for (int kb = 0; kb < KB; ++kb) {
    short8v a = ap[kb * 4];
#pragma unroll
    for (int nb = 0; nb < NBh; ++nb) {
      short8v b = bp[(kb * NBf + chh * NBh + nb) * 64 + lane];
      acc[nb] = __builtin_amdgcn_mfma_f32_16x16x32_bf16(a, b, acc[nb], 0, 0, 0);
    }
  }
  int r0 = (lane >> 4) * 4;
  int coll = lane & 15;
#pragma unroll
  for (int nb = 0; nb < NBh; ++nb) {
    int col = (chh * NBh + nb) * 16 + coll;
    float bv = bias[col];
    float s = 0.f, q = 0.f;
#pragma unroll
    for (int r = 0; r < 4; ++r) {
      long long row = row0 + r0 + r;
      float v = acc[nb][r] + bv;
      outp[row * NOUT + col] = f2bf(v);
      s += v; q += v * v;
    }
    s += __shfl_xor(s, 16); q += __shfl_xor(q, 16);
    s += __shfl_xor(s, 32); q += __shfl_xor(q, 32);
    if (kgrp == 0) { atomicAdd(&ls[col], s); atomicAdd(&lq[col], q); }
  }
  __syncthreads();
  if (threadIdx.x < NOUT) {
    atomicAdd(&stats[threadIdx.x], ls[threadIdx.x]);
    atomicAdd(&stats[NOUT + threadIdx.x], lq[threadIdx.x]);
  }
}

// ---- FC GEMM, col-split x2, per-block BN finalize, fused BN->ReLU->bf16 A-op ----
template<int K, int NOUT, int OUT_BF16>
__global__ void fcgemm_kernel(const unsigned short* __restrict__ Af,
                              const unsigned short* __restrict__ Bp,
                              const float* __restrict__ stats, const float* __restrict__ g,
                              const float* __restrict__ be, const float* __restrict__ bias,
                              void* __restrict__ outp) {
  constexpr int NBf = NOUT / 16;
  constexpr int NBh = NOUT / 32;
  constexpr int KB = K / 32;
  __shared__ float sc[K], sh[K];
  if (threadIdx.x < K) {
    float mean = stats[threadIdx.x] * (1.0f / N_NODES);
    float var = stats[K + threadIdx.x] * (1.0f / N_NODES) - mean * mean;
    float rstd = rsqrtf(var + BN_EPS);
    float s = g[threadIdx.x] * rstd;
    sc[threadIdx.x] = s;
    sh[threadIdx.x] = be[threadIdx.x] - mean * s;
  }
  __syncthreads();
  int gw = (blockIdx.x * blockDim.x + threadIdx.x) >> 6;
  int lane = threadIdx.x & 63;
  int rt = gw >> 1, chh = gw & 1;
  int row0 = rt * 16;
  int arow = row0 + (lane & 15);
  int kgrp = lane >> 4;
  f32x4 acc[NBh];
#pragma unroll
  for (int i = 0; i < NBh; ++i) acc[i] = (f32x4){0.f, 0.f, 0.f, 0.f};
  const short8v* ap = (const short8v*)(Af + (long long)arow * K + kgrp * 8);
  const short8v* bp = (const short8v*)Bp;
#pragma unroll
  for (int kb = 0; kb < KB; ++kb) {
    short8v raw = ap[kb * 4];
    int kk = kb * 32 + kgrp * 8;
    short8v a;
#pragma unroll
    for (int j = 0; j < 8; ++j) {
      float v = bf2f((unsigned int)(unsigned short)raw[j]);
      a[j] = (short)f2bf(fmaxf(fmaf(v, sc[kk + j], sh[kk + j]), 0.f));
    }
#pragma unroll
    for (int nb = 0; nb < NBh; ++nb) {
      short8v b = bp[(kb * NBf + chh * NBh + nb) * 64 + lane];
      acc[nb] = __builtin_amdgcn_mfma_f32_16x16x32_bf16(a, b, acc[nb], 0, 0, 0);
    }
  }
  int r0 = (lane >> 4) * 4;
  int coll = lane & 15;
#pragma unroll
  for (int nb = 0; nb < NBh; ++nb) {
    int col = (chh * NBh + nb) * 16 + coll;
    float bv = bias[col];
#pragma unroll
    for (int r = 0; r < 4; ++r) {
      long long row = row0 + r0 + r;
      float v = acc[nb][r] + bv;
      if (OUT_BF16) ((unsigned short*)outp)[row * NOUT + col] = f2bf(v);
      else ((float*)outp)[row * NOUT + col] = v;
    }
  }
}

extern "C" void kernel_launch(void* const* d_in, const int* in_sizes, int n_in,
                              void* d_out, int out_size, void* d_ws, size_t ws_size,
                              hipStream_t stream) {
  const int N = N_NODES;
  const float* x = (const float*)d_in[0];
  const int* src[3] = {(const int*)d_in[1], (const int*)d_in[3], (const int*)d_in[5]};
  const int* dst[3] = {(const int*)d_in[2], (const int*)d_in[4], (const int*)d_in[6]};
  const int E[3] = {in_sizes[1], in_sizes[3], in_sizes[5]};
  const int E_tot = E[0] + E[1] + E[2];

  const float* w0[3] = {(const float*)d_in[7], (const float*)d_in[9], (const float*)d_in[11]};
  const float* b0[3] = {(const float*)d_in[8], (const float*)d_in[10], (const float*)d_in[12]};
  const float* bn0_g = (const float*)d_in[13];
  const float* bn0_b = (const float*)d_in[14];
  const float* fc0_w = (const float*)d_in[15];
  const float* fc0_b = (const float*)d_in[16];
  const float* w1[3] = {(const float*)d_in[17], (const float*)d_in[19], (const float*)d_in[21]};
  const float* b1[3] = {(const float*)d_in[18], (const float*)d_in[20], (const float*)d_in[22]};
  const float* bn1_g = (const float*)d_in[23];
  const float* bn1_b = (const float*)d_in[24];
  const float* fc1_w = (const float*)d_in[25];
  const float* fc1_b = (const float*)d_in[26];

  // ---- workspace layout (~87.6 MB, under proven 93.2) ----
  char* p = (char*)d_ws;
  auto alloc = [&](size_t bytes) { char* r = p; p += (bytes + 255) & ~255ULL; return r; };
  float* rs_out = (float*)alloc((size_t)3 * N * 4);
  float* rs_in = (float*)alloc((size_t)3 * N * 4);
  int* row_ptr = (int*)alloc((size_t)3 * (N + 1) * 4);
  int* bbaseS = (int*)alloc((size_t)3 * (NBKT + 1) * 4);
  int* bbaseD = (int*)alloc((size_t)3 * (NBKT + 1) * 4);
  int* partial = (int*)alloc((size_t)2 * 3 * NCHK * 256 * 4);
  unsigned int* es = (unsigned int*)alloc((size_t)E_tot * 4);
  unsigned char* tmp8 = (unsigned char*)alloc((size_t)E_tot);   // own region (fixes r13 overlap bug)
  unsigned short* wpk = (unsigned short*)alloc((size_t)(18432 + 36864 + 9216 + 16384) * 2);
  float* b0s = (float*)alloc(96 * 4);
  float* b1s = (float*)alloc(128 * 4);
  float* statsA = (float*)alloc(192 * 4);
  float* statsB = (float*)alloc(256 * 4);
  unsigned short* xb = (unsigned short*)alloc((size_t)N * 64 * 2);   // own buffer (prep runs early)
  unsigned short* aggC = (unsigned short*)alloc((size_t)N * 288 * 2);
  unsigned short* hsum = (unsigned short*)alloc((size_t)N * 128 * 2); // bf16; hosts overlays early
  unsigned short* h1 = (unsigned short*)alloc((size_t)N * 96 * 2);

  unsigned short* B0p = wpk;                          // 192x96
  unsigned short* B1p = wpk + 18432;                  // 288x128
  unsigned short* fc0p = wpk + 18432 + 36864;         // 96x96
  unsigned short* fc1p = wpk + 18432 + 36864 + 9216;  // 128x128

  // transient aliases inside hsum region (16.38MB; all dead before gemm0 writes hsum)
  // tmp [0, 8.19MB) | HistS [11MB, 12.5MB) | HistD [13MB, 14.5MB) -- disjoint
  unsigned int* tmp = (unsigned int*)hsum;
  int* HistS = (int*)((char*)hsum + ((size_t)11 << 20));
  int* HistD = (int*)((char*)hsum + ((size_t)13 << 20));

  // ---- CSR build + prep (prep blocks run concurrently with histogram blocks) ----
  r1p_kernel<<<R1_BLOCKS + cdiv(PREP_ITEMS, 256), 256, 0, stream>>>(
      src[0], src[1], src[2], dst[0], dst[1], dst[2], E[0], E[1], E[2], HistS, HistD,
      x, xb, w0[0], w0[1], w0[2], w1[0], w1[1], w1[2], fc0_w, fc1_w,
      b0[0], b0[1], b0[2], b1[0], b1[1], b1[2], B0p, B1p, fc0p, fc1p, b0s, b1s, statsA, statsB);
  r2a_kernel<<<192, 256, 0, stream>>>(HistS, HistD, partial);
  r2b_kernel<<<6, 256, 0, stream>>>(partial, bbaseS, bbaseD);
  r2c_kernel<<<192, 256, 0, stream>>>(HistS, HistD, partial);
  r3ab_kernel<<<3 * NBL, 256, 0, stream>>>(src[0], src[1], src[2], dst[0], dst[1], dst[2],
                                           E[0], E[1], E[2], HistS, HistD, tmp, tmp8);
  r4b_kernel<<<3 * NBKT, 256, 0, stream>>>(tmp8, bbaseS, E[0], E[1], E[2], rs_out);
  r4_kernel<<<3 * NBKT, 256, 0, stream>>>(tmp, bbaseD, E[0], E[1], E[2], rs_out,
                                          es, row_ptr, rs_in);

  const int B = 256;
  const int GEMM_BLOCKS = N / 16 * 2 * 64 / B;  // 2000: 2 col-half waves per 16-row tile

  // ---- layer 0 ----
  gather3_kernel<64, 192><<<cdiv((long long)3 * N * 64, B), B, 0, stream>>>(
      (const unsigned int*)xb, row_ptr, es, rs_in, (unsigned int*)aggC, E[0], E[0] + E[1]);
  gemm_kernel<192, 96><<<GEMM_BLOCKS, B, 0, stream>>>(aggC, B0p, b0s, hsum, statsA);
  fcgemm_kernel<96, 96, 1><<<GEMM_BLOCKS, B, 0, stream>>>(hsum, fc0p, statsA, bn0_g, bn0_b,
                                                          fc0_b, h1);

  // ---- layer 1 ----
  gather3_kernel<96, 288><<<cdiv((long long)3 * N * 64, B), B, 0, stream>>>(
      (const unsigned int*)h1, row_ptr, es, rs_in, (unsigned int*)aggC, E[0], E[0] + E[1]);
  gemm_kernel<288, 128><<<GEMM_BLOCKS, B, 0, stream>>>(aggC, B1p, b1s, hsum, statsB);
  fcgemm_kernel<128, 128, 0><<<GEMM_BLOCKS, B, 0, stream>>>(hsum, fc1p, statsB, bn1_g, bn1_b,
                                                            fc1_b, (float*)d_out);
}